// Round 11
// baseline (210.445 us; speedup 1.0000x reference)
//
#include <hip/hip_runtime.h>

#define EPS 1e-6f
#define LL 4096
#define HE 512

typedef __attribute__((ext_vector_type(8))) short short8;
typedef __attribute__((ext_vector_type(4))) float f32x4;
typedef __attribute__((ext_vector_type(2))) unsigned u32x2;
typedef __attribute__((ext_vector_type(4))) unsigned u32x4;

__device__ __forceinline__ unsigned short f2bf(float f) {
    union { float f; unsigned u; } v; v.f = f;
    unsigned r = v.u + 0x7FFFu + ((v.u >> 16) & 1u);  // RNE
    return (unsigned short)(r >> 16);
}
__device__ __forceinline__ float bf2f(unsigned short s) {
    union { unsigned u; float f; } v; v.u = ((unsigned)s) << 16;
    return v.f;
}
// async global->LDS, 16B per lane; LDS dest = wave-uniform base + lane*16
__device__ __forceinline__ void gl16(const unsigned short* g, unsigned short* l) {
    __builtin_amdgcn_global_load_lds(
        (const __attribute__((address_space(1))) unsigned int*)(const void*)g,
        (__attribute__((address_space(3))) unsigned int*)(void*)l,
        16, 0, 0);
}
__device__ __forceinline__ unsigned lds_addr(const void* p) {
    return (unsigned)(unsigned long long)(const __attribute__((address_space(3))) char*)p;
}
// transpose read: lane gets column (addr%128)/8 of the [4][16] bf16 subtile
#define TRREAD(dst, addr, IMM) \
    asm volatile("ds_read_b64_tr_b16 %0, %1 offset:%2" : "=v"(dst) : "v"(addr), "i"(IMM))

union S8U { u32x4 u; short8 s; };

// ---- k1: pure streaming: q -> Vb (bf16 [l][n]) + column-stat partials ----
__global__ __launch_bounds__(256) void k1_stream(const float* __restrict__ q,
        unsigned short* __restrict__ Vb, float* __restrict__ ps,
        float* __restrict__ pq) {
    __shared__ float lds_s[4][512];
    __shared__ float lds_q[4][512];
    int blk = blockIdx.x;
    int b = blk >> 6, lt = blk & 63;
    int t = threadIdx.x;
    int oct = t & 63, w = t >> 6;
    size_t rowbase = (size_t)b * LL + lt * 64 + w * 16;
    const float* qb = q + rowbase * HE + oct * 8;
    unsigned short* vb = Vb + rowbase * HE + oct * 8;
    float s[8] = {}, qq[8] = {};
    #pragma unroll
    for (int r = 0; r < 16; r++) {
        float4 v0 = *(const float4*)(qb + (size_t)r * HE);
        float4 v1 = *(const float4*)(qb + (size_t)r * HE + 4);
        unsigned short e[8] = {f2bf(v0.x), f2bf(v0.y), f2bf(v0.z), f2bf(v0.w),
                               f2bf(v1.x), f2bf(v1.y), f2bf(v1.z), f2bf(v1.w)};
        short8 w8;
        #pragma unroll
        for (int c = 0; c < 8; c++) {
            w8[c] = (short)e[c];
            float x = bf2f(e[c]);
            s[c] += x; qq[c] += x * x;
        }
        *(short8*)(vb + (size_t)r * HE) = w8;
    }
    #pragma unroll
    for (int c = 0; c < 8; c++) {
        lds_s[w][oct * 8 + c] = s[c];
        lds_q[w][oct * 8 + c] = qq[c];
    }
    __syncthreads();
    #pragma unroll
    for (int h = 0; h < 2; h++) {
        int col = h * 256 + t;
        float ss = lds_s[0][col] + lds_s[1][col] + lds_s[2][col] + lds_s[3][col];
        float sq = lds_q[0][col] + lds_q[1][col] + lds_q[2][col] + lds_q[3][col];
        ps[(size_t)lt * 8192 + b * 512 + col] = ss;
        pq[(size_t)lt * 8192 + b * 512 + col] = sq;
    }
}

// ---- k2: reduce partials -> sumV, cvec, invn ----------------------------
__global__ __launch_bounds__(256) void k2_reduce(const float* __restrict__ ps,
        const float* __restrict__ pq, float* __restrict__ sumV,
        float* __restrict__ cvec, float* __restrict__ invn) {
    int i = blockIdx.x * 256 + threadIdx.x;   // 0..8191 = b*512 + n
    float s = 0.f, qq = 0.f;
    #pragma unroll 8
    for (int lt = 0; lt < 64; lt++) {
        s  += ps[(size_t)lt * 8192 + i];
        qq += pq[(size_t)lt * 8192 + i];
    }
    float inv = 1.0f / sqrtf(qq);
    sumV[i] = s;
    invn[i] = inv;
    cvec[i] = (s * inv + EPS) * inv;
}

// ---- k4: Gram partials straight from Vb via subtiled LDS + tr_b16 reads --
// Stage [64 l][128 n] panels with gl16 into [lgrp][ngrp][4][16] layout;
// fragments via ds_read_b64_tr_b16. 2-phase counted-vmcnt pipeline (r5).
__global__ __launch_bounds__(256) void k4_gram(const unsigned short* __restrict__ Vb,
        unsigned short* __restrict__ Gp) {
    __shared__ __attribute__((aligned(16))) unsigned short la[2][8192];
    __shared__ __attribute__((aligned(16))) unsigned short lb[2][8192];
    int cpx = gridDim.x >> 3;
    int blk = ((int)blockIdx.x & 7) * cpx + ((int)blockIdx.x >> 3);  // XCD swizzle
    int b = blk / 80;
    int rem = blk - b * 80;
    int pair = rem >> 3, split = rem & 7;
    int nt = (pair < 4) ? 0 : (pair < 7) ? 1 : (pair < 9) ? 2 : 3;
    int off = (nt * (9 - nt)) >> 1;
    int mt = nt + pair - off;
    bool diag = (nt == mt);
    int N0 = nt * 128, M0 = mt * 128;
    int t = threadIdx.x;
    int w = t >> 6, lane = t & 63;
    int wr = w >> 1, wc = w & 1;
    int lr = lane & 15, q4 = lane >> 4;
    // staging source decode: lane covers subtile elems lane*8..lane*8+7
    int srcRow = (lane >> 1) & 3;                    // l within lgrp
    int srcCol = (lane >> 3) * 16 + (lane & 1) * 8;  // n within 128
    const unsigned short* pa = Vb + ((size_t)b * LL + split * 512) * HE + N0;
    const unsigned short* pb = Vb + ((size_t)b * LL + split * 512) * HE + M0;
    // tr-read base addresses (per buffer, per operand role)
    unsigned laneTr = (unsigned)((lane >> 4) * 2048 + (lane & 15) * 8);
    unsigned rdA0 = lds_addr(&la[0][0]) + wr * 512 + laneTr;
    unsigned rdA1 = lds_addr(&la[1][0]) + wr * 512 + laneTr;
    unsigned rdB0 = (diag ? lds_addr(&la[0][0]) : lds_addr(&lb[0][0])) + wc * 512 + laneTr;
    unsigned rdB1 = (diag ? lds_addr(&la[1][0]) : lds_addr(&lb[1][0])) + wc * 512 + laneTr;
    f32x4 acc[4][4] = {};

#define STG(B, KB) do { \
    _Pragma("unroll") \
    for (int lg = 0; lg < 4; lg++) { \
        size_t ro = (size_t)((KB) * 64 + w * 16 + lg * 4 + srcRow) * HE + srcCol; \
        gl16(pa + ro, &la[B][(w * 4 + lg) * 512]); \
        if (!diag) gl16(pb + ro, &lb[B][(w * 4 + lg) * 512]); \
    } } while (0)

#define FRAGS_MFMA(KS, AADDR, BADDR) do { \
    u32x2 a0[4], a1[4], b0[4], b1[4]; \
    TRREAD(a0[0], AADDR, (KS)*8192 + 0*128);        TRREAD(a1[0], AADDR, (KS)*8192 + 0*128 + 1024); \
    TRREAD(a0[1], AADDR, (KS)*8192 + 1*128);        TRREAD(a1[1], AADDR, (KS)*8192 + 1*128 + 1024); \
    TRREAD(a0[2], AADDR, (KS)*8192 + 2*128);        TRREAD(a1[2], AADDR, (KS)*8192 + 2*128 + 1024); \
    TRREAD(a0[3], AADDR, (KS)*8192 + 3*128);        TRREAD(a1[3], AADDR, (KS)*8192 + 3*128 + 1024); \
    TRREAD(b0[0], BADDR, (KS)*8192 + 0*128);        TRREAD(b1[0], BADDR, (KS)*8192 + 0*128 + 1024); \
    TRREAD(b0[1], BADDR, (KS)*8192 + 1*128);        TRREAD(b1[1], BADDR, (KS)*8192 + 1*128 + 1024); \
    TRREAD(b0[2], BADDR, (KS)*8192 + 2*128);        TRREAD(b1[2], BADDR, (KS)*8192 + 2*128 + 1024); \
    TRREAD(b0[3], BADDR, (KS)*8192 + 3*128);        TRREAD(b1[3], BADDR, (KS)*8192 + 3*128 + 1024); \
    asm volatile("s_waitcnt lgkmcnt(0)" ::: "memory"); \
    __builtin_amdgcn_sched_barrier(0); \
    short8 af[4], bfr[4]; \
    _Pragma("unroll") \
    for (int i = 0; i < 4; i++) { \
        S8U ua; ua.u = (u32x4){a0[i].x, a0[i].y, a1[i].x, a1[i].y}; af[i] = ua.s; \
        S8U ub; ub.u = (u32x4){b0[i].x, b0[i].y, b1[i].x, b1[i].y}; bfr[i] = ub.s; \
    } \
    _Pragma("unroll") \
    for (int i = 0; i < 4; i++) \
        _Pragma("unroll") \
        for (int j = 0; j < 4; j++) \
            acc[i][j] = __builtin_amdgcn_mfma_f32_16x16x32_bf16(af[i], bfr[j], acc[i][j], 0, 0, 0); \
    } while (0)

    STG(0, 0);  // prologue
    #pragma unroll
    for (int kb = 0; kb < 8; kb++) {
        int cur = kb & 1;
        if (kb < 7) {
            STG(cur ^ 1, kb + 1);
            if (diag) { asm volatile("s_waitcnt vmcnt(4)" ::: "memory"); }
            else      { asm volatile("s_waitcnt vmcnt(8)" ::: "memory"); }
        } else {
            asm volatile("s_waitcnt vmcnt(0)" ::: "memory");
        }
        __builtin_amdgcn_s_barrier();
        __builtin_amdgcn_sched_barrier(0);
        unsigned aAd = cur ? rdA1 : rdA0;
        unsigned bAd = cur ? rdB1 : rdB0;
        FRAGS_MFMA(0, aAd, bAd);
        FRAGS_MFMA(1, aAd, bAd);
        __builtin_amdgcn_s_barrier();
    }
#undef STG
#undef FRAGS_MFMA
    // store bf16 partials, layout [ml*128 + nl] -> ushort4 along n
    size_t tbase = ((size_t)(b * 10 + pair) * 8 + split) * 16384;
    #pragma unroll
    for (int i = 0; i < 4; i++) {
        int nb = wr * 64 + i * 16 + q4 * 4;
        #pragma unroll
        for (int j = 0; j < 4; j++) {
            int ml = wc * 64 + j * 16 + lr;
            ushort4 wv;
            wv.x = f2bf(acc[i][j][0]); wv.y = f2bf(acc[i][j][1]);
            wv.z = f2bf(acc[i][j][2]); wv.w = f2bf(acc[i][j][3]);
            *(ushort4*)&Gp[tbase + (size_t)ml * 128 + nb] = wv;
        }
    }
}

// ---- k5: sum splits, scale by invn outer, write KQb both orientations ---
__global__ __launch_bounds__(256) void k5_reduce(const unsigned short* __restrict__ Gp,
        const float* __restrict__ invn, unsigned short* __restrict__ KQb) {
    __shared__ unsigned short lds_t[128][130];
    int blk = blockIdx.x;
    int b = blk / 10, pair = blk % 10;
    int nt = (pair < 4) ? 0 : (pair < 7) ? 1 : (pair < 9) ? 2 : 3;
    int off = (nt * (9 - nt)) >> 1;
    int mt = nt + pair - off;
    int N0 = nt * 128, M0 = mt * 128;
    int t = threadIdx.x;
    const unsigned short* gp = Gp + ((size_t)(b * 10 + pair) * 8) * 16384;
    const float* inb = invn + (size_t)b * HE;
    #pragma unroll 2
    for (int e = 0; e < 32; e++) {
        int idx = e * 512 + t * 2;           // [ml][nl] pairs
        int ml = idx >> 7, nl = idx & 127;
        float s0 = 0.f, s1 = 0.f;
        #pragma unroll
        for (int sp = 0; sp < 8; sp++) {
            unsigned g2 = *(const unsigned*)&gp[(size_t)sp * 16384 + idx];
            s0 += bf2f((unsigned short)(g2 & 0xFFFF));
            s1 += bf2f((unsigned short)(g2 >> 16));
        }
        float im = inb[M0 + ml];
        ushort2 v;
        v.x = f2bf(s0 * inb[N0 + nl] * im);
        v.y = f2bf(s1 * inb[N0 + nl + 1] * im);
        *(ushort2*)&KQb[((size_t)b * HE + M0 + ml) * HE + N0 + nl] = v;
        *(ushort2*)&lds_t[ml][nl] = v;
    }
    __syncthreads();
    #pragma unroll 2
    for (int e = 0; e < 32; e++) {
        int idx = e * 512 + t * 2;
        int nl = idx >> 7, ml = idx & 127;   // transposed roles
        ushort2 v;
        v.x = lds_t[ml][nl];
        v.y = lds_t[ml + 1][nl];
        *(ushort2*)&KQb[((size_t)b * HE + N0 + nl) * HE + M0 + ml] = v;
    }
}

// ---- k6: part GEMM (KQb x Vb) + FUSED tailor dot + epilogue -------------
// 2-phase counted-vmcnt pipeline; tailor dot accumulates from staged lb[cur].
__global__ __launch_bounds__(256) void k6_part(const unsigned short* __restrict__ KQb,
        const unsigned short* __restrict__ Vb, const float* __restrict__ cvec,
        const float* __restrict__ sumV, const float* __restrict__ gamma,
        float* __restrict__ out) {
    __shared__ __attribute__((aligned(16))) unsigned short la[2][128][64];
    __shared__ __attribute__((aligned(16))) unsigned short lb[2][128][64];
    __shared__ float lds_c[512];
    __shared__ float lds_d[128][2];
    int cpx = gridDim.x >> 3;
    int blk = ((int)blockIdx.x & 7) * cpx + ((int)blockIdx.x >> 3);  // XCD swizzle
    int b = blk >> 7, mt = (blk >> 5) & 3, lt = blk & 31;
    int M0 = mt * 128, L0 = lt * 128;
    int t = threadIdx.x;
    int w = t >> 6, lane = t & 63;
    int wr = w >> 1, wc = w & 1;
    int rl = lane >> 3;
    int cl = ((lane & 7) ^ rl) << 3;
    int lr = lane & 15, q4 = lane >> 4;
    int ch0 = (q4 ^ (lane & 7)) << 3;
    const unsigned short* pa = KQb + ((size_t)b * HE + M0) * HE;
    const unsigned short* pb = Vb + ((size_t)b * LL + L0) * HE;
    float gma = gamma[0];
    lds_c[t]       = cvec[b * HE + t];
    lds_c[t + 256] = cvec[b * HE + t + 256];
    __syncthreads();           // before any gl16 issues; vmcnt still clean
    f32x4 acc[4][4] = {};
    float dpart = 0.f;
    int drow = t >> 1, dsw = (t >> 1) & 7, dh = t & 1;

#define STAGE6(B, KB) do { \
    int _k0 = (KB) * 64; \
    _Pragma("unroll") \
    for (int p = 0; p < 4; p++) { \
        int r0 = p * 32 + w * 8; \
        gl16(pa + (size_t)(r0 + rl) * HE + _k0 + cl, &la[B][r0][0]); \
        gl16(pb + (size_t)(r0 + rl) * HE + _k0 + cl, &lb[B][r0][0]); \
    } } while (0)

    STAGE6(0, 0);  // prologue
    #pragma unroll
    for (int kb = 0; kb < 8; kb++) {
        int cur = kb & 1;
        if (kb < 7) {
            STAGE6(cur ^ 1, kb + 1);
            asm volatile("s_waitcnt vmcnt(8)" ::: "memory");
        } else {
            asm volatile("s_waitcnt vmcnt(0)" ::: "memory");
        }
        __builtin_amdgcn_s_barrier();
        // fused tailor dot on this K-step's B tile (rows = l, cols = n-slice)
        {
            int k0 = kb * 64;
            #pragma unroll
            for (int ch = 0; ch < 4; ch++) {
                int g = dh * 4 + ch;
                short8 v = *(const short8*)&lb[cur][drow][(g ^ dsw) << 3];
                const float* cp = &lds_c[k0 + g * 8];
                dpart += bf2f((unsigned short)v[0]) * cp[0] + bf2f((unsigned short)v[1]) * cp[1]
                       + bf2f((unsigned short)v[2]) * cp[2] + bf2f((unsigned short)v[3]) * cp[3]
                       + bf2f((unsigned short)v[4]) * cp[4] + bf2f((unsigned short)v[5]) * cp[5]
                       + bf2f((unsigned short)v[6]) * cp[6] + bf2f((unsigned short)v[7]) * cp[7];
            }
        }
        #pragma unroll
        for (int ks = 0; ks < 2; ks++) {
            int colA = ch0 ^ (ks << 5);
            short8 af[4], bfr[4];
            #pragma unroll
            for (int i = 0; i < 4; i++)
                af[i] = *(const short8*)&la[cur][wr*64 + i*16 + lr][colA];
            #pragma unroll
            for (int j = 0; j < 4; j++)
                bfr[j] = *(const short8*)&lb[cur][wc*64 + j*16 + lr][colA];
            #pragma unroll
            for (int i = 0; i < 4; i++)
                #pragma unroll
                for (int j = 0; j < 4; j++)
                    acc[i][j] = __builtin_amdgcn_mfma_f32_16x16x32_bf16(af[i], bfr[j], acc[i][j], 0, 0, 0);
        }
        __builtin_amdgcn_s_barrier();
    }
#undef STAGE6
    lds_d[drow][dh] = dpart;
    __syncthreads();
    #pragma unroll
    for (int j = 0; j < 4; j++) {
        int lloc = wc*64 + j*16 + lr;
        int lglob = L0 + lloc;
        float dt = lds_d[lloc][0] + lds_d[lloc][1];
        float tailor = 1.0f / (512.0f + dt);
        #pragma unroll
        for (int i = 0; i < 4; i++) {
            int m4 = M0 + wr*64 + i*16 + q4*4;
            size_t ofs = ((size_t)b * LL + lglob) * HE + m4;
            ushort4 rv = *(const ushort4*)(Vb + ((size_t)b * LL + lglob) * HE + m4);
            float4 vs = *(const float4*)(sumV + (size_t)b * HE + m4);
            float4 o;
            o.x = bf2f(rv.x) + gma * (vs.x + acc[i][j][0]) * tailor;
            o.y = bf2f(rv.y) + gma * (vs.y + acc[i][j][1]) * tailor;
            o.z = bf2f(rv.z) + gma * (vs.z + acc[i][j][2]) * tailor;
            o.w = bf2f(rv.w) + gma * (vs.w + acc[i][j][3]) * tailor;
            *(float4*)(out + ofs) = o;
        }
    }
}

extern "C" void kernel_launch(void* const* d_in, const int* in_sizes, int n_in,
                              void* d_out, int out_size, void* d_ws, size_t ws_size,
                              hipStream_t stream) {
    const float* q     = (const float*)d_in[0];
    const float* gamma = (const float*)d_in[4];
    float* out = (float*)d_out;
    char* ws = (char*)d_ws;
    // ws layout (~122 MiB; proven r6)
    float* sumV  = (float*)(ws);                          // 32 KiB
    float* cvec  = (float*)(ws + 65536);                  // 32 KiB
    float* invn  = (float*)(ws + 98304);                  // 32 KiB
    unsigned short* KQb = (unsigned short*)(ws + 524288);      // 8 MiB
    unsigned short* Vb  = (unsigned short*)(ws + 8912896);     // 64 MiB
    unsigned short* Gp  = (unsigned short*)(ws + 76021760);    // 40 MiB
    float* ps = (float*)(ws + 117964800);                 // 2 MiB
    float* pq = (float*)(ws + 120061952);                 // 2 MiB

    k1_stream<<<1024, 256, 0, stream>>>(q, Vb, ps, pq);
    k2_reduce<<<32,   256, 0, stream>>>(ps, pq, sumV, cvec, invn);
    k4_gram  <<<1280, 256, 0, stream>>>(Vb, Gp);
    k5_reduce<<<160,  256, 0, stream>>>(Gp, invn, KQb);
    k6_part  <<<2048, 256, 0, stream>>>(KQb, Vb, cvec, sumV, gamma, out);
}

// Round 12
// 193.790 us; speedup vs baseline: 1.0859x; 1.0859x over previous
//
#include <hip/hip_runtime.h>

#define EPS 1e-6f
#define LL 4096
#define HE 512

typedef __attribute__((ext_vector_type(8))) short short8;
typedef __attribute__((ext_vector_type(4))) float f32x4;
typedef __attribute__((ext_vector_type(2))) unsigned u32x2;
typedef __attribute__((ext_vector_type(4))) unsigned u32x4;

__device__ __forceinline__ unsigned short f2bf(float f) {
    union { float f; unsigned u; } v; v.f = f;
    unsigned r = v.u + 0x7FFFu + ((v.u >> 16) & 1u);  // RNE
    return (unsigned short)(r >> 16);
}
__device__ __forceinline__ float bf2f(unsigned short s) {
    union { unsigned u; float f; } v; v.u = ((unsigned)s) << 16;
    return v.f;
}
// async global->LDS, 16B per lane; LDS dest = wave-uniform base + lane*16
__device__ __forceinline__ void gl16(const unsigned short* g, unsigned short* l) {
    __builtin_amdgcn_global_load_lds(
        (const __attribute__((address_space(1))) unsigned int*)(const void*)g,
        (__attribute__((address_space(3))) unsigned int*)(void*)l,
        16, 0, 0);
}
__device__ __forceinline__ unsigned lds_addr(const void* p) {
    return (unsigned)(unsigned long long)(const __attribute__((address_space(3))) char*)p;
}
// transpose read: lane gets column (addr%128)/8 of the [4][16] bf16 subtile
#define TRREAD(dst, addr, IMM) \
    asm volatile("ds_read_b64_tr_b16 %0, %1 offset:%2" : "=v"(dst) : "v"(addr), "i"(IMM))

union S8U { u32x4 u; short8 s; };

// ---- k1: pure streaming: q -> Vb (bf16 [l][n]) + column-stat partials ----
__global__ __launch_bounds__(256) void k1_stream(const float* __restrict__ q,
        unsigned short* __restrict__ Vb, float* __restrict__ ps,
        float* __restrict__ pq) {
    __shared__ float lds_s[4][512];
    __shared__ float lds_q[4][512];
    int blk = blockIdx.x;
    int b = blk >> 6, lt = blk & 63;
    int t = threadIdx.x;
    int oct = t & 63, w = t >> 6;
    size_t rowbase = (size_t)b * LL + lt * 64 + w * 16;
    const float* qb = q + rowbase * HE + oct * 8;
    unsigned short* vb = Vb + rowbase * HE + oct * 8;
    float s[8] = {}, qq[8] = {};
    #pragma unroll
    for (int r = 0; r < 16; r++) {
        float4 v0 = *(const float4*)(qb + (size_t)r * HE);
        float4 v1 = *(const float4*)(qb + (size_t)r * HE + 4);
        unsigned short e[8] = {f2bf(v0.x), f2bf(v0.y), f2bf(v0.z), f2bf(v0.w),
                               f2bf(v1.x), f2bf(v1.y), f2bf(v1.z), f2bf(v1.w)};
        short8 w8;
        #pragma unroll
        for (int c = 0; c < 8; c++) {
            w8[c] = (short)e[c];
            float x = bf2f(e[c]);
            s[c] += x; qq[c] += x * x;
        }
        *(short8*)(vb + (size_t)r * HE) = w8;
    }
    #pragma unroll
    for (int c = 0; c < 8; c++) {
        lds_s[w][oct * 8 + c] = s[c];
        lds_q[w][oct * 8 + c] = qq[c];
    }
    __syncthreads();
    #pragma unroll
    for (int h = 0; h < 2; h++) {
        int col = h * 256 + t;
        float ss = lds_s[0][col] + lds_s[1][col] + lds_s[2][col] + lds_s[3][col];
        float sq = lds_q[0][col] + lds_q[1][col] + lds_q[2][col] + lds_q[3][col];
        ps[(size_t)lt * 8192 + b * 512 + col] = ss;
        pq[(size_t)lt * 8192 + b * 512 + col] = sq;
    }
}

// ---- k2: reduce partials -> sumV, cvec, invn ----------------------------
__global__ __launch_bounds__(256) void k2_reduce(const float* __restrict__ ps,
        const float* __restrict__ pq, float* __restrict__ sumV,
        float* __restrict__ cvec, float* __restrict__ invn) {
    int i = blockIdx.x * 256 + threadIdx.x;   // 0..8191 = b*512 + n
    float s = 0.f, qq = 0.f;
    #pragma unroll 8
    for (int lt = 0; lt < 64; lt++) {
        s  += ps[(size_t)lt * 8192 + i];
        qq += pq[(size_t)lt * 8192 + i];
    }
    float inv = 1.0f / sqrtf(qq);
    sumV[i] = s;
    invn[i] = inv;
    cvec[i] = (s * inv + EPS) * inv;
}

// ---- k3: dvec[b,l] = sum_n Vb[l,n]*cvec[n]  (GEMV) ----------------------
__global__ __launch_bounds__(256) void k3_dvec(const unsigned short* __restrict__ Vb,
        const float* __restrict__ cvec, float* __restrict__ dvec) {
    int blk = blockIdx.x;
    int b = blk >> 7, lblk = blk & 127;
    int t = threadIdx.x;
    int lloc = t >> 3, j = t & 7;
    int l = lblk * 32 + lloc;
    const unsigned short* rowp = Vb + ((size_t)b * LL + l) * HE + j * 64;
    const float* cp = cvec + b * HE + j * 64;
    float d = 0.f;
    #pragma unroll
    for (int g = 0; g < 8; g++) {
        short8 v = *(const short8*)(rowp + g * 8);
        float4 c0 = *(const float4*)(cp + g * 8);
        float4 c1 = *(const float4*)(cp + g * 8 + 4);
        d += bf2f((unsigned short)v[0]) * c0.x + bf2f((unsigned short)v[1]) * c0.y
           + bf2f((unsigned short)v[2]) * c0.z + bf2f((unsigned short)v[3]) * c0.w
           + bf2f((unsigned short)v[4]) * c1.x + bf2f((unsigned short)v[5]) * c1.y
           + bf2f((unsigned short)v[6]) * c1.z + bf2f((unsigned short)v[7]) * c1.w;
    }
    d += __shfl_xor(d, 1); d += __shfl_xor(d, 2); d += __shfl_xor(d, 4);
    if (j == 0) dvec[(size_t)b * LL + l] = d;
}

// ---- k4: Gram partials straight from Vb via subtiled LDS + tr_b16 reads --
// (r11-proven: ~28 us, correct) Stage [64 l][128 n] panels with gl16 into
// [lgrp][ngrp][4][16] layout; fragments via ds_read_b64_tr_b16.
__global__ __launch_bounds__(256) void k4_gram(const unsigned short* __restrict__ Vb,
        unsigned short* __restrict__ Gp) {
    __shared__ __attribute__((aligned(16))) unsigned short la[2][8192];
    __shared__ __attribute__((aligned(16))) unsigned short lb[2][8192];
    int cpx = gridDim.x >> 3;
    int blk = ((int)blockIdx.x & 7) * cpx + ((int)blockIdx.x >> 3);  // XCD swizzle
    int b = blk / 80;
    int rem = blk - b * 80;
    int pair = rem >> 3, split = rem & 7;
    int nt = (pair < 4) ? 0 : (pair < 7) ? 1 : (pair < 9) ? 2 : 3;
    int off = (nt * (9 - nt)) >> 1;
    int mt = nt + pair - off;
    bool diag = (nt == mt);
    int N0 = nt * 128, M0 = mt * 128;
    int t = threadIdx.x;
    int w = t >> 6, lane = t & 63;
    int wr = w >> 1, wc = w & 1;
    int lr = lane & 15, q4 = lane >> 4;
    int srcRow = (lane >> 1) & 3;                    // l within lgrp
    int srcCol = (lane >> 3) * 16 + (lane & 1) * 8;  // n within 128
    const unsigned short* pa = Vb + ((size_t)b * LL + split * 512) * HE + N0;
    const unsigned short* pb = Vb + ((size_t)b * LL + split * 512) * HE + M0;
    unsigned laneTr = (unsigned)((lane >> 4) * 2048 + (lane & 15) * 8);
    unsigned rdA0 = lds_addr(&la[0][0]) + wr * 512 + laneTr;
    unsigned rdA1 = lds_addr(&la[1][0]) + wr * 512 + laneTr;
    unsigned rdB0 = (diag ? lds_addr(&la[0][0]) : lds_addr(&lb[0][0])) + wc * 512 + laneTr;
    unsigned rdB1 = (diag ? lds_addr(&la[1][0]) : lds_addr(&lb[1][0])) + wc * 512 + laneTr;
    f32x4 acc[4][4] = {};

#define STG(B, KB) do { \
    _Pragma("unroll") \
    for (int lg = 0; lg < 4; lg++) { \
        size_t ro = (size_t)((KB) * 64 + w * 16 + lg * 4 + srcRow) * HE + srcCol; \
        gl16(pa + ro, &la[B][(w * 4 + lg) * 512]); \
        if (!diag) gl16(pb + ro, &lb[B][(w * 4 + lg) * 512]); \
    } } while (0)

#define FRAGS_MFMA(KS, AADDR, BADDR) do { \
    u32x2 a0[4], a1[4], b0[4], b1[4]; \
    TRREAD(a0[0], AADDR, (KS)*8192 + 0*128);        TRREAD(a1[0], AADDR, (KS)*8192 + 0*128 + 1024); \
    TRREAD(a0[1], AADDR, (KS)*8192 + 1*128);        TRREAD(a1[1], AADDR, (KS)*8192 + 1*128 + 1024); \
    TRREAD(a0[2], AADDR, (KS)*8192 + 2*128);        TRREAD(a1[2], AADDR, (KS)*8192 + 2*128 + 1024); \
    TRREAD(a0[3], AADDR, (KS)*8192 + 3*128);        TRREAD(a1[3], AADDR, (KS)*8192 + 3*128 + 1024); \
    TRREAD(b0[0], BADDR, (KS)*8192 + 0*128);        TRREAD(b1[0], BADDR, (KS)*8192 + 0*128 + 1024); \
    TRREAD(b0[1], BADDR, (KS)*8192 + 1*128);        TRREAD(b1[1], BADDR, (KS)*8192 + 1*128 + 1024); \
    TRREAD(b0[2], BADDR, (KS)*8192 + 2*128);        TRREAD(b1[2], BADDR, (KS)*8192 + 2*128 + 1024); \
    TRREAD(b0[3], BADDR, (KS)*8192 + 3*128);        TRREAD(b1[3], BADDR, (KS)*8192 + 3*128 + 1024); \
    asm volatile("s_waitcnt lgkmcnt(0)" ::: "memory"); \
    __builtin_amdgcn_sched_barrier(0); \
    short8 af[4], bfr[4]; \
    _Pragma("unroll") \
    for (int i = 0; i < 4; i++) { \
        S8U ua; ua.u = (u32x4){a0[i].x, a0[i].y, a1[i].x, a1[i].y}; af[i] = ua.s; \
        S8U ub; ub.u = (u32x4){b0[i].x, b0[i].y, b1[i].x, b1[i].y}; bfr[i] = ub.s; \
    } \
    _Pragma("unroll") \
    for (int i = 0; i < 4; i++) \
        _Pragma("unroll") \
        for (int j = 0; j < 4; j++) \
            acc[i][j] = __builtin_amdgcn_mfma_f32_16x16x32_bf16(af[i], bfr[j], acc[i][j], 0, 0, 0); \
    } while (0)

    STG(0, 0);  // prologue
    #pragma unroll
    for (int kb = 0; kb < 8; kb++) {
        int cur = kb & 1;
        if (kb < 7) {
            STG(cur ^ 1, kb + 1);
            if (diag) { asm volatile("s_waitcnt vmcnt(4)" ::: "memory"); }
            else      { asm volatile("s_waitcnt vmcnt(8)" ::: "memory"); }
        } else {
            asm volatile("s_waitcnt vmcnt(0)" ::: "memory");
        }
        __builtin_amdgcn_s_barrier();
        __builtin_amdgcn_sched_barrier(0);
        unsigned aAd = cur ? rdA1 : rdA0;
        unsigned bAd = cur ? rdB1 : rdB0;
        FRAGS_MFMA(0, aAd, bAd);
        FRAGS_MFMA(1, aAd, bAd);
        __builtin_amdgcn_s_barrier();
    }
#undef STG
#undef FRAGS_MFMA
    // store bf16 partials, layout [ml*128 + nl] -> ushort4 along n
    size_t tbase = ((size_t)(b * 10 + pair) * 8 + split) * 16384;
    #pragma unroll
    for (int i = 0; i < 4; i++) {
        int nb = wr * 64 + i * 16 + q4 * 4;
        #pragma unroll
        for (int j = 0; j < 4; j++) {
            int ml = wc * 64 + j * 16 + lr;
            ushort4 wv;
            wv.x = f2bf(acc[i][j][0]); wv.y = f2bf(acc[i][j][1]);
            wv.z = f2bf(acc[i][j][2]); wv.w = f2bf(acc[i][j][3]);
            *(ushort4*)&Gp[tbase + (size_t)ml * 128 + nb] = wv;
        }
    }
}

// ---- k5: sum splits, scale by invn outer, write KQb both orientations ---
__global__ __launch_bounds__(256) void k5_reduce(const unsigned short* __restrict__ Gp,
        const float* __restrict__ invn, unsigned short* __restrict__ KQb) {
    __shared__ unsigned short lds_t[128][130];
    int blk = blockIdx.x;
    int b = blk / 10, pair = blk % 10;
    int nt = (pair < 4) ? 0 : (pair < 7) ? 1 : (pair < 9) ? 2 : 3;
    int off = (nt * (9 - nt)) >> 1;
    int mt = nt + pair - off;
    int N0 = nt * 128, M0 = mt * 128;
    int t = threadIdx.x;
    const unsigned short* gp = Gp + ((size_t)(b * 10 + pair) * 8) * 16384;
    const float* inb = invn + (size_t)b * HE;
    #pragma unroll 2
    for (int e = 0; e < 32; e++) {
        int idx = e * 512 + t * 2;           // [ml][nl] pairs
        int ml = idx >> 7, nl = idx & 127;
        float s0 = 0.f, s1 = 0.f;
        #pragma unroll
        for (int sp = 0; sp < 8; sp++) {
            unsigned g2 = *(const unsigned*)&gp[(size_t)sp * 16384 + idx];
            s0 += bf2f((unsigned short)(g2 & 0xFFFF));
            s1 += bf2f((unsigned short)(g2 >> 16));
        }
        float im = inb[M0 + ml];
        ushort2 v;
        v.x = f2bf(s0 * inb[N0 + nl] * im);
        v.y = f2bf(s1 * inb[N0 + nl + 1] * im);
        *(ushort2*)&KQb[((size_t)b * HE + M0 + ml) * HE + N0 + nl] = v;
        *(ushort2*)&lds_t[ml][nl] = v;
    }
    __syncthreads();
    #pragma unroll 2
    for (int e = 0; e < 32; e++) {
        int idx = e * 512 + t * 2;
        int nl = idx >> 7, ml = idx & 127;   // transposed roles
        ushort2 v;
        v.x = lds_t[ml][nl];
        v.y = lds_t[ml + 1][nl];
        *(ushort2*)&KQb[((size_t)b * HE + N0 + nl) * HE + M0 + ml] = v;
    }
}

// ---- k6: part GEMM (KQb x Vb) + tailor/sumV/residual epilogue -----------
// r5/r10-proven: 2-phase double-buffered, counted vmcnt, 92 VGPR.
__global__ __launch_bounds__(256) void k6_part(const unsigned short* __restrict__ KQb,
        const unsigned short* __restrict__ Vb, const float* __restrict__ dvec,
        const float* __restrict__ sumV, const float* __restrict__ gamma,
        float* __restrict__ out) {
    __shared__ __attribute__((aligned(16))) unsigned short la[2][128][64];
    __shared__ __attribute__((aligned(16))) unsigned short lb[2][128][64];
    int cpx = gridDim.x >> 3;
    int blk = ((int)blockIdx.x & 7) * cpx + ((int)blockIdx.x >> 3);  // XCD swizzle
    int b = blk >> 7, mt = (blk >> 5) & 3, lt = blk & 31;
    int M0 = mt * 128, L0 = lt * 128;
    int t = threadIdx.x;
    int w = t >> 6, lane = t & 63;
    int wr = w >> 1, wc = w & 1;
    int rl = lane >> 3;
    int cl = ((lane & 7) ^ rl) << 3;
    int lr = lane & 15, q4 = lane >> 4;
    int ch0 = (q4 ^ (lane & 7)) << 3;
    const unsigned short* pa = KQb + ((size_t)b * HE + M0) * HE;
    const unsigned short* pb = Vb + ((size_t)b * LL + L0) * HE;
    float gma = gamma[0];   // hoisted above prologue so vmcnt counting stays exact
    f32x4 acc[4][4] = {};

#define STAGE6(B, KB) do { \
    int _k0 = (KB) * 64; \
    _Pragma("unroll") \
    for (int p = 0; p < 4; p++) { \
        int r0 = p * 32 + w * 8; \
        gl16(pa + (size_t)(r0 + rl) * HE + _k0 + cl, &la[B][r0][0]); \
        gl16(pb + (size_t)(r0 + rl) * HE + _k0 + cl, &lb[B][r0][0]); \
    } } while (0)

    STAGE6(0, 0);  // prologue
    #pragma unroll
    for (int kb = 0; kb < 8; kb++) {
        int cur = kb & 1;
        if (kb < 7) {
            STAGE6(cur ^ 1, kb + 1);
            asm volatile("s_waitcnt vmcnt(8)" ::: "memory");
        } else {
            asm volatile("s_waitcnt vmcnt(0)" ::: "memory");
        }
        __builtin_amdgcn_s_barrier();
        #pragma unroll
        for (int ks = 0; ks < 2; ks++) {
            int colA = ch0 ^ (ks << 5);
            short8 af[4], bfr[4];
            #pragma unroll
            for (int i = 0; i < 4; i++)
                af[i] = *(const short8*)&la[cur][wr*64 + i*16 + lr][colA];
            #pragma unroll
            for (int j = 0; j < 4; j++)
                bfr[j] = *(const short8*)&lb[cur][wc*64 + j*16 + lr][colA];
            #pragma unroll
            for (int i = 0; i < 4; i++)
                #pragma unroll
                for (int j = 0; j < 4; j++)
                    acc[i][j] = __builtin_amdgcn_mfma_f32_16x16x32_bf16(af[i], bfr[j], acc[i][j], 0, 0, 0);
        }
        __builtin_amdgcn_s_barrier();
    }
#undef STAGE6
    #pragma unroll
    for (int j = 0; j < 4; j++) {
        int lglob = L0 + wc*64 + j*16 + lr;
        float dt = dvec[(size_t)b * LL + lglob];
        float tailor = 1.0f / (512.0f + dt);
        #pragma unroll
        for (int i = 0; i < 4; i++) {
            int m4 = M0 + wr*64 + i*16 + q4*4;
            size_t ofs = ((size_t)b * LL + lglob) * HE + m4;
            ushort4 rv = *(const ushort4*)(Vb + ((size_t)b * LL + lglob) * HE + m4);
            float4 vs = *(const float4*)(sumV + (size_t)b * HE + m4);
            float4 o;
            o.x = bf2f(rv.x) + gma * (vs.x + acc[i][j][0]) * tailor;
            o.y = bf2f(rv.y) + gma * (vs.y + acc[i][j][1]) * tailor;
            o.z = bf2f(rv.z) + gma * (vs.z + acc[i][j][2]) * tailor;
            o.w = bf2f(rv.w) + gma * (vs.w + acc[i][j][3]) * tailor;
            *(float4*)(out + ofs) = o;
        }
    }
}

extern "C" void kernel_launch(void* const* d_in, const int* in_sizes, int n_in,
                              void* d_out, int out_size, void* d_ws, size_t ws_size,
                              hipStream_t stream) {
    const float* q     = (const float*)d_in[0];
    const float* gamma = (const float*)d_in[4];
    float* out = (float*)d_out;
    char* ws = (char*)d_ws;
    // ws layout (~122 MiB; proven r6)
    float* sumV  = (float*)(ws);                          // 32 KiB
    float* cvec  = (float*)(ws + 65536);                  // 32 KiB
    float* invn  = (float*)(ws + 98304);                  // 32 KiB
    float* dvec  = (float*)(ws + 131072);                 // 256 KiB
    unsigned short* KQb = (unsigned short*)(ws + 524288);      // 8 MiB
    unsigned short* Vb  = (unsigned short*)(ws + 8912896);     // 64 MiB
    unsigned short* Gp  = (unsigned short*)(ws + 76021760);    // 40 MiB
    float* ps = (float*)(ws + 117964800);                 // 2 MiB
    float* pq = (float*)(ws + 120061952);                 // 2 MiB

    k1_stream<<<1024, 256, 0, stream>>>(q, Vb, ps, pq);
    k2_reduce<<<32,   256, 0, stream>>>(ps, pq, sumV, cvec, invn);
    k3_dvec  <<<2048, 256, 0, stream>>>(Vb, cvec, dvec);
    k4_gram  <<<1280, 256, 0, stream>>>(Vb, Gp);
    k5_reduce<<<160,  256, 0, stream>>>(Gp, invn, KQb);
    k6_part  <<<2048, 256, 0, stream>>>(KQb, Vb, dvec, sumV, gamma, out);
}

// Round 13
// 188.222 us; speedup vs baseline: 1.1181x; 1.0296x over previous
//
#include <hip/hip_runtime.h>

#define EPS 1e-6f
#define LL 4096
#define HE 512

typedef __attribute__((ext_vector_type(8))) short short8;
typedef __attribute__((ext_vector_type(4))) float f32x4;
typedef __attribute__((ext_vector_type(2))) unsigned u32x2;
typedef __attribute__((ext_vector_type(4))) unsigned u32x4;

__device__ __forceinline__ unsigned short f2bf(float f) {
    union { float f; unsigned u; } v; v.f = f;
    unsigned r = v.u + 0x7FFFu + ((v.u >> 16) & 1u);  // RNE
    return (unsigned short)(r >> 16);
}
__device__ __forceinline__ float bf2f(unsigned short s) {
    union { unsigned u; float f; } v; v.u = ((unsigned)s) << 16;
    return v.f;
}
// async global->LDS, 16B per lane; LDS dest = wave-uniform base + lane*16
__device__ __forceinline__ void gl16(const unsigned short* g, unsigned short* l) {
    __builtin_amdgcn_global_load_lds(
        (const __attribute__((address_space(1))) unsigned int*)(const void*)g,
        (__attribute__((address_space(3))) unsigned int*)(void*)l,
        16, 0, 0);
}
__device__ __forceinline__ unsigned lds_addr(const void* p) {
    return (unsigned)(unsigned long long)(const __attribute__((address_space(3))) char*)p;
}
// transpose read: lane gets column (addr%128)/8 of the [4][16] bf16 subtile
#define TRREAD(dst, addr, IMM) \
    asm volatile("ds_read_b64_tr_b16 %0, %1 offset:%2" : "=v"(dst) : "v"(addr), "i"(IMM))

union S8U { u32x4 u; short8 s; };

// ---- k1: pure streaming: q -> Vb (bf16 [l][n]) + column-stat partials ----
__global__ __launch_bounds__(256) void k1_stream(const float* __restrict__ q,
        unsigned short* __restrict__ Vb, float* __restrict__ ps,
        float* __restrict__ pq) {
    __shared__ float lds_s[4][512];
    __shared__ float lds_q[4][512];
    int blk = blockIdx.x;
    int b = blk >> 6, lt = blk & 63;
    int t = threadIdx.x;
    int oct = t & 63, w = t >> 6;
    size_t rowbase = (size_t)b * LL + lt * 64 + w * 16;
    const float* qb = q + rowbase * HE + oct * 8;
    unsigned short* vb = Vb + rowbase * HE + oct * 8;
    float s[8] = {}, qq[8] = {};
    #pragma unroll
    for (int r = 0; r < 16; r++) {
        float4 v0 = *(const float4*)(qb + (size_t)r * HE);
        float4 v1 = *(const float4*)(qb + (size_t)r * HE + 4);
        unsigned short e[8] = {f2bf(v0.x), f2bf(v0.y), f2bf(v0.z), f2bf(v0.w),
                               f2bf(v1.x), f2bf(v1.y), f2bf(v1.z), f2bf(v1.w)};
        short8 w8;
        #pragma unroll
        for (int c = 0; c < 8; c++) {
            w8[c] = (short)e[c];
            float x = bf2f(e[c]);
            s[c] += x; qq[c] += x * x;
        }
        *(short8*)(vb + (size_t)r * HE) = w8;
    }
    #pragma unroll
    for (int c = 0; c < 8; c++) {
        lds_s[w][oct * 8 + c] = s[c];
        lds_q[w][oct * 8 + c] = qq[c];
    }
    __syncthreads();
    #pragma unroll
    for (int h = 0; h < 2; h++) {
        int col = h * 256 + t;
        float ss = lds_s[0][col] + lds_s[1][col] + lds_s[2][col] + lds_s[3][col];
        float sq = lds_q[0][col] + lds_q[1][col] + lds_q[2][col] + lds_q[3][col];
        ps[(size_t)lt * 8192 + b * 512 + col] = ss;
        pq[(size_t)lt * 8192 + b * 512 + col] = sq;
    }
}

// ---- k2: reduce partials -> sumV, cvec, invn ----------------------------
__global__ __launch_bounds__(256) void k2_reduce(const float* __restrict__ ps,
        const float* __restrict__ pq, float* __restrict__ sumV,
        float* __restrict__ cvec, float* __restrict__ invn) {
    int i = blockIdx.x * 256 + threadIdx.x;   // 0..8191 = b*512 + n
    float s = 0.f, qq = 0.f;
    #pragma unroll 8
    for (int lt = 0; lt < 64; lt++) {
        s  += ps[(size_t)lt * 8192 + i];
        qq += pq[(size_t)lt * 8192 + i];
    }
    float inv = 1.0f / sqrtf(qq);
    sumV[i] = s;
    invn[i] = inv;
    cvec[i] = (s * inv + EPS) * inv;
}

// ---- k3: dvec[b,l] = sum_n Vb[l,n]*cvec[n]  (GEMV) ----------------------
__global__ __launch_bounds__(256) void k3_dvec(const unsigned short* __restrict__ Vb,
        const float* __restrict__ cvec, float* __restrict__ dvec) {
    int blk = blockIdx.x;
    int b = blk >> 7, lblk = blk & 127;
    int t = threadIdx.x;
    int lloc = t >> 3, j = t & 7;
    int l = lblk * 32 + lloc;
    const unsigned short* rowp = Vb + ((size_t)b * LL + l) * HE + j * 64;
    const float* cp = cvec + b * HE + j * 64;
    float d = 0.f;
    #pragma unroll
    for (int g = 0; g < 8; g++) {
        short8 v = *(const short8*)(rowp + g * 8);
        float4 c0 = *(const float4*)(cp + g * 8);
        float4 c1 = *(const float4*)(cp + g * 8 + 4);
        d += bf2f((unsigned short)v[0]) * c0.x + bf2f((unsigned short)v[1]) * c0.y
           + bf2f((unsigned short)v[2]) * c0.z + bf2f((unsigned short)v[3]) * c0.w
           + bf2f((unsigned short)v[4]) * c1.x + bf2f((unsigned short)v[5]) * c1.y
           + bf2f((unsigned short)v[6]) * c1.z + bf2f((unsigned short)v[7]) * c1.w;
    }
    d += __shfl_xor(d, 1); d += __shfl_xor(d, 2); d += __shfl_xor(d, 4);
    if (j == 0) dvec[(size_t)b * LL + l] = d;
}

// ---- k4: Gram partials from Vb via subtiled LDS + tr_b16 reads ----------
// split-K=4 (each block K=1024, 16 K-steps): halves Gp traffic vs split-8.
__global__ __launch_bounds__(256) void k4_gram(const unsigned short* __restrict__ Vb,
        unsigned short* __restrict__ Gp) {
    __shared__ __attribute__((aligned(16))) unsigned short la[2][8192];
    __shared__ __attribute__((aligned(16))) unsigned short lb[2][8192];
    int cpx = gridDim.x >> 3;
    int blk = ((int)blockIdx.x & 7) * cpx + ((int)blockIdx.x >> 3);  // XCD swizzle
    int b = blk / 40;
    int rem = blk - b * 40;
    int pair = rem >> 2, split = rem & 3;
    int nt = (pair < 4) ? 0 : (pair < 7) ? 1 : (pair < 9) ? 2 : 3;
    int off = (nt * (9 - nt)) >> 1;
    int mt = nt + pair - off;
    bool diag = (nt == mt);
    int N0 = nt * 128, M0 = mt * 128;
    int t = threadIdx.x;
    int w = t >> 6, lane = t & 63;
    int wr = w >> 1, wc = w & 1;
    int lr = lane & 15, q4 = lane >> 4;
    int srcRow = (lane >> 1) & 3;                    // l within lgrp
    int srcCol = (lane >> 3) * 16 + (lane & 1) * 8;  // n within 128
    const unsigned short* pa = Vb + ((size_t)b * LL + split * 1024) * HE + N0;
    const unsigned short* pb = Vb + ((size_t)b * LL + split * 1024) * HE + M0;
    unsigned laneTr = (unsigned)((lane >> 4) * 2048 + (lane & 15) * 8);
    unsigned rdA0 = lds_addr(&la[0][0]) + wr * 512 + laneTr;
    unsigned rdA1 = lds_addr(&la[1][0]) + wr * 512 + laneTr;
    unsigned rdB0 = (diag ? lds_addr(&la[0][0]) : lds_addr(&lb[0][0])) + wc * 512 + laneTr;
    unsigned rdB1 = (diag ? lds_addr(&la[1][0]) : lds_addr(&lb[1][0])) + wc * 512 + laneTr;
    f32x4 acc[4][4] = {};

#define STG(B, KB) do { \
    _Pragma("unroll") \
    for (int lg = 0; lg < 4; lg++) { \
        size_t ro = (size_t)((KB) * 64 + w * 16 + lg * 4 + srcRow) * HE + srcCol; \
        gl16(pa + ro, &la[B][(w * 4 + lg) * 512]); \
        if (!diag) gl16(pb + ro, &lb[B][(w * 4 + lg) * 512]); \
    } } while (0)

#define FRAGS_MFMA(KS, AADDR, BADDR) do { \
    u32x2 a0[4], a1[4], b0[4], b1[4]; \
    TRREAD(a0[0], AADDR, (KS)*8192 + 0*128);        TRREAD(a1[0], AADDR, (KS)*8192 + 0*128 + 1024); \
    TRREAD(a0[1], AADDR, (KS)*8192 + 1*128);        TRREAD(a1[1], AADDR, (KS)*8192 + 1*128 + 1024); \
    TRREAD(a0[2], AADDR, (KS)*8192 + 2*128);        TRREAD(a1[2], AADDR, (KS)*8192 + 2*128 + 1024); \
    TRREAD(a0[3], AADDR, (KS)*8192 + 3*128);        TRREAD(a1[3], AADDR, (KS)*8192 + 3*128 + 1024); \
    TRREAD(b0[0], BADDR, (KS)*8192 + 0*128);        TRREAD(b1[0], BADDR, (KS)*8192 + 0*128 + 1024); \
    TRREAD(b0[1], BADDR, (KS)*8192 + 1*128);        TRREAD(b1[1], BADDR, (KS)*8192 + 1*128 + 1024); \
    TRREAD(b0[2], BADDR, (KS)*8192 + 2*128);        TRREAD(b1[2], BADDR, (KS)*8192 + 2*128 + 1024); \
    TRREAD(b0[3], BADDR, (KS)*8192 + 3*128);        TRREAD(b1[3], BADDR, (KS)*8192 + 3*128 + 1024); \
    asm volatile("s_waitcnt lgkmcnt(0)" ::: "memory"); \
    __builtin_amdgcn_sched_barrier(0); \
    short8 af[4], bfr[4]; \
    _Pragma("unroll") \
    for (int i = 0; i < 4; i++) { \
        S8U ua; ua.u = (u32x4){a0[i].x, a0[i].y, a1[i].x, a1[i].y}; af[i] = ua.s; \
        S8U ub; ub.u = (u32x4){b0[i].x, b0[i].y, b1[i].x, b1[i].y}; bfr[i] = ub.s; \
    } \
    _Pragma("unroll") \
    for (int i = 0; i < 4; i++) \
        _Pragma("unroll") \
        for (int j = 0; j < 4; j++) \
            acc[i][j] = __builtin_amdgcn_mfma_f32_16x16x32_bf16(af[i], bfr[j], acc[i][j], 0, 0, 0); \
    } while (0)

    STG(0, 0);  // prologue
    #pragma unroll
    for (int kb = 0; kb < 16; kb++) {
        int cur = kb & 1;
        if (kb < 15) {
            STG(cur ^ 1, kb + 1);
            if (diag) { asm volatile("s_waitcnt vmcnt(4)" ::: "memory"); }
            else      { asm volatile("s_waitcnt vmcnt(8)" ::: "memory"); }
        } else {
            asm volatile("s_waitcnt vmcnt(0)" ::: "memory");
        }
        __builtin_amdgcn_s_barrier();
        __builtin_amdgcn_sched_barrier(0);
        unsigned aAd = cur ? rdA1 : rdA0;
        unsigned bAd = cur ? rdB1 : rdB0;
        FRAGS_MFMA(0, aAd, bAd);
        FRAGS_MFMA(1, aAd, bAd);
        __builtin_amdgcn_s_barrier();
    }
#undef STG
#undef FRAGS_MFMA
    // store bf16 partials, layout [ml*128 + nl] -> ushort4 along n
    size_t tbase = ((size_t)(b * 10 + pair) * 4 + split) * 16384;
    #pragma unroll
    for (int i = 0; i < 4; i++) {
        int nb = wr * 64 + i * 16 + q4 * 4;
        #pragma unroll
        for (int j = 0; j < 4; j++) {
            int ml = wc * 64 + j * 16 + lr;
            ushort4 wv;
            wv.x = f2bf(acc[i][j][0]); wv.y = f2bf(acc[i][j][1]);
            wv.z = f2bf(acc[i][j][2]); wv.w = f2bf(acc[i][j][3]);
            *(ushort4*)&Gp[tbase + (size_t)ml * 128 + nb] = wv;
        }
    }
}

// ---- k5: sum 4 splits, scale by invn outer, write KQb both orientations -
__global__ __launch_bounds__(256) void k5_reduce(const unsigned short* __restrict__ Gp,
        const float* __restrict__ invn, unsigned short* __restrict__ KQb) {
    __shared__ unsigned short lds_t[128][130];
    int blk = blockIdx.x;
    int b = blk / 10, pair = blk % 10;
    int nt = (pair < 4) ? 0 : (pair < 7) ? 1 : (pair < 9) ? 2 : 3;
    int off = (nt * (9 - nt)) >> 1;
    int mt = nt + pair - off;
    int N0 = nt * 128, M0 = mt * 128;
    int t = threadIdx.x;
    const unsigned short* gp = Gp + ((size_t)(b * 10 + pair) * 4) * 16384;
    const float* inb = invn + (size_t)b * HE;
    #pragma unroll 2
    for (int e = 0; e < 32; e++) {
        int idx = e * 512 + t * 2;           // [ml][nl] pairs
        int ml = idx >> 7, nl = idx & 127;
        float s0 = 0.f, s1 = 0.f;
        #pragma unroll
        for (int sp = 0; sp < 4; sp++) {
            unsigned g2 = *(const unsigned*)&gp[(size_t)sp * 16384 + idx];
            s0 += bf2f((unsigned short)(g2 & 0xFFFF));
            s1 += bf2f((unsigned short)(g2 >> 16));
        }
        float im = inb[M0 + ml];
        ushort2 v;
        v.x = f2bf(s0 * inb[N0 + nl] * im);
        v.y = f2bf(s1 * inb[N0 + nl + 1] * im);
        *(ushort2*)&KQb[((size_t)b * HE + M0 + ml) * HE + N0 + nl] = v;
        *(ushort2*)&lds_t[ml][nl] = v;
    }
    __syncthreads();
    #pragma unroll 2
    for (int e = 0; e < 32; e++) {
        int idx = e * 512 + t * 2;
        int nl = idx >> 7, ml = idx & 127;   // transposed roles
        ushort2 v;
        v.x = lds_t[ml][nl];
        v.y = lds_t[ml + 1][nl];
        *(ushort2*)&KQb[((size_t)b * HE + N0 + nl) * HE + M0 + ml] = v;
    }
}

// ---- k6: part GEMM (KQb x Vb) + tailor/sumV/residual epilogue -----------
// r5/r10-proven: 2-phase double-buffered, counted vmcnt, 92 VGPR.
__global__ __launch_bounds__(256) void k6_part(const unsigned short* __restrict__ KQb,
        const unsigned short* __restrict__ Vb, const float* __restrict__ dvec,
        const float* __restrict__ sumV, const float* __restrict__ gamma,
        float* __restrict__ out) {
    __shared__ __attribute__((aligned(16))) unsigned short la[2][128][64];
    __shared__ __attribute__((aligned(16))) unsigned short lb[2][128][64];
    int cpx = gridDim.x >> 3;
    int blk = ((int)blockIdx.x & 7) * cpx + ((int)blockIdx.x >> 3);  // XCD swizzle
    int b = blk >> 7, mt = (blk >> 5) & 3, lt = blk & 31;
    int M0 = mt * 128, L0 = lt * 128;
    int t = threadIdx.x;
    int w = t >> 6, lane = t & 63;
    int wr = w >> 1, wc = w & 1;
    int rl = lane >> 3;
    int cl = ((lane & 7) ^ rl) << 3;
    int lr = lane & 15, q4 = lane >> 4;
    int ch0 = (q4 ^ (lane & 7)) << 3;
    const unsigned short* pa = KQb + ((size_t)b * HE + M0) * HE;
    const unsigned short* pb = Vb + ((size_t)b * LL + L0) * HE;
    float gma = gamma[0];   // hoisted above prologue so vmcnt counting stays exact
    f32x4 acc[4][4] = {};

#define STAGE6(B, KB) do { \
    int _k0 = (KB) * 64; \
    _Pragma("unroll") \
    for (int p = 0; p < 4; p++) { \
        int r0 = p * 32 + w * 8; \
        gl16(pa + (size_t)(r0 + rl) * HE + _k0 + cl, &la[B][r0][0]); \
        gl16(pb + (size_t)(r0 + rl) * HE + _k0 + cl, &lb[B][r0][0]); \
    } } while (0)

    STAGE6(0, 0);  // prologue
    #pragma unroll
    for (int kb = 0; kb < 8; kb++) {
        int cur = kb & 1;
        if (kb < 7) {
            STAGE6(cur ^ 1, kb + 1);
            asm volatile("s_waitcnt vmcnt(8)" ::: "memory");
        } else {
            asm volatile("s_waitcnt vmcnt(0)" ::: "memory");
        }
        __builtin_amdgcn_s_barrier();
        #pragma unroll
        for (int ks = 0; ks < 2; ks++) {
            int colA = ch0 ^ (ks << 5);
            short8 af[4], bfr[4];
            #pragma unroll
            for (int i = 0; i < 4; i++)
                af[i] = *(const short8*)&la[cur][wr*64 + i*16 + lr][colA];
            #pragma unroll
            for (int j = 0; j < 4; j++)
                bfr[j] = *(const short8*)&lb[cur][wc*64 + j*16 + lr][colA];
            #pragma unroll
            for (int i = 0; i < 4; i++)
                #pragma unroll
                for (int j = 0; j < 4; j++)
                    acc[i][j] = __builtin_amdgcn_mfma_f32_16x16x32_bf16(af[i], bfr[j], acc[i][j], 0, 0, 0);
        }
        __builtin_amdgcn_s_barrier();
    }
#undef STAGE6
    #pragma unroll
    for (int j = 0; j < 4; j++) {
        int lglob = L0 + wc*64 + j*16 + lr;
        float dt = dvec[(size_t)b * LL + lglob];
        float tailor = 1.0f / (512.0f + dt);
        #pragma unroll
        for (int i = 0; i < 4; i++) {
            int m4 = M0 + wr*64 + i*16 + q4*4;
            size_t ofs = ((size_t)b * LL + lglob) * HE + m4;
            ushort4 rv = *(const ushort4*)(Vb + ((size_t)b * LL + lglob) * HE + m4);
            float4 vs = *(const float4*)(sumV + (size_t)b * HE + m4);
            float4 o;
            o.x = bf2f(rv.x) + gma * (vs.x + acc[i][j][0]) * tailor;
            o.y = bf2f(rv.y) + gma * (vs.y + acc[i][j][1]) * tailor;
            o.z = bf2f(rv.z) + gma * (vs.z + acc[i][j][2]) * tailor;
            o.w = bf2f(rv.w) + gma * (vs.w + acc[i][j][3]) * tailor;
            *(float4*)(out + ofs) = o;
        }
    }
}

extern "C" void kernel_launch(void* const* d_in, const int* in_sizes, int n_in,
                              void* d_out, int out_size, void* d_ws, size_t ws_size,
                              hipStream_t stream) {
    const float* q     = (const float*)d_in[0];
    const float* gamma = (const float*)d_in[4];
    float* out = (float*)d_out;
    char* ws = (char*)d_ws;
    // ws layout (~122 MiB; proven r6)
    float* sumV  = (float*)(ws);                          // 32 KiB
    float* cvec  = (float*)(ws + 65536);                  // 32 KiB
    float* invn  = (float*)(ws + 98304);                  // 32 KiB
    float* dvec  = (float*)(ws + 131072);                 // 256 KiB
    unsigned short* KQb = (unsigned short*)(ws + 524288);      // 8 MiB
    unsigned short* Vb  = (unsigned short*)(ws + 8912896);     // 64 MiB
    unsigned short* Gp  = (unsigned short*)(ws + 76021760);    // 21 MiB (split-4)
    float* ps = (float*)(ws + 117964800);                 // 2 MiB
    float* pq = (float*)(ws + 120061952);                 // 2 MiB

    k1_stream<<<1024, 256, 0, stream>>>(q, Vb, ps, pq);
    k2_reduce<<<32,   256, 0, stream>>>(ps, pq, sumV, cvec, invn);
    k3_dvec  <<<2048, 256, 0, stream>>>(Vb, cvec, dvec);
    k4_gram  <<<640,  256, 0, stream>>>(Vb, Gp);
    k5_reduce<<<160,  256, 0, stream>>>(Gp, invn, KQb);
    k6_part  <<<2048, 256, 0, stream>>>(KQb, Vb, dvec, sumV, gamma, out);
}

// Round 14
// 173.375 us; speedup vs baseline: 1.2138x; 1.0856x over previous
//
#include <hip/hip_runtime.h>

#define EPS 1e-6f
#define LL 4096
#define HE 512

typedef __attribute__((ext_vector_type(8))) short short8;
typedef __attribute__((ext_vector_type(4))) float f32x4;
typedef __attribute__((ext_vector_type(2))) unsigned u32x2;
typedef __attribute__((ext_vector_type(4))) unsigned u32x4;

__device__ __forceinline__ unsigned short f2bf(float f) {
    union { float f; unsigned u; } v; v.f = f;
    unsigned r = v.u + 0x7FFFu + ((v.u >> 16) & 1u);  // RNE
    return (unsigned short)(r >> 16);
}
__device__ __forceinline__ float bf2f(unsigned short s) {
    union { unsigned u; float f; } v; v.u = ((unsigned)s) << 16;
    return v.f;
}
// async global->LDS, 16B per lane; LDS dest = wave-uniform base + lane*16
__device__ __forceinline__ void gl16(const unsigned short* g, unsigned short* l) {
    __builtin_amdgcn_global_load_lds(
        (const __attribute__((address_space(1))) unsigned int*)(const void*)g,
        (__attribute__((address_space(3))) unsigned int*)(void*)l,
        16, 0, 0);
}
__device__ __forceinline__ unsigned lds_addr(const void* p) {
    return (unsigned)(unsigned long long)(const __attribute__((address_space(3))) char*)p;
}
// transpose read: lane gets column (addr%128)/8 of the [4][16] bf16 subtile
#define TRREAD(dst, addr, IMM) \
    asm volatile("ds_read_b64_tr_b16 %0, %1 offset:%2" : "=v"(dst) : "v"(addr), "i"(IMM))

union S8U { u32x4 u; short8 s; };

// ---- k1: pure streaming: q -> Vb (bf16 [l][n]) + column-stat partials ----
__global__ __launch_bounds__(256) void k1_stream(const float* __restrict__ q,
        unsigned short* __restrict__ Vb, float* __restrict__ ps,
        float* __restrict__ pq) {
    __shared__ float lds_s[4][512];
    __shared__ float lds_q[4][512];
    int blk = blockIdx.x;
    int b = blk >> 6, lt = blk & 63;
    int t = threadIdx.x;
    int oct = t & 63, w = t >> 6;
    size_t rowbase = (size_t)b * LL + lt * 64 + w * 16;
    const float* qb = q + rowbase * HE + oct * 8;
    unsigned short* vb = Vb + rowbase * HE + oct * 8;
    float s[8] = {}, qq[8] = {};
    #pragma unroll
    for (int r = 0; r < 16; r++) {
        float4 v0 = *(const float4*)(qb + (size_t)r * HE);
        float4 v1 = *(const float4*)(qb + (size_t)r * HE + 4);
        unsigned short e[8] = {f2bf(v0.x), f2bf(v0.y), f2bf(v0.z), f2bf(v0.w),
                               f2bf(v1.x), f2bf(v1.y), f2bf(v1.z), f2bf(v1.w)};
        short8 w8;
        #pragma unroll
        for (int c = 0; c < 8; c++) {
            w8[c] = (short)e[c];
            float x = bf2f(e[c]);
            s[c] += x; qq[c] += x * x;
        }
        *(short8*)(vb + (size_t)r * HE) = w8;
    }
    #pragma unroll
    for (int c = 0; c < 8; c++) {
        lds_s[w][oct * 8 + c] = s[c];
        lds_q[w][oct * 8 + c] = qq[c];
    }
    __syncthreads();
    #pragma unroll
    for (int h = 0; h < 2; h++) {
        int col = h * 256 + t;
        float ss = lds_s[0][col] + lds_s[1][col] + lds_s[2][col] + lds_s[3][col];
        float sq = lds_q[0][col] + lds_q[1][col] + lds_q[2][col] + lds_q[3][col];
        ps[(size_t)lt * 8192 + b * 512 + col] = ss;
        pq[(size_t)lt * 8192 + b * 512 + col] = sq;
    }
}

// ---- kA: fused k4 (gram, blocks 0..639) + k2 (stats reduce, 640..671) ----
__global__ __launch_bounds__(256) void kA_gram_stats(
        const unsigned short* __restrict__ Vb, unsigned short* __restrict__ Gp,
        const float* __restrict__ ps, const float* __restrict__ pq,
        float* __restrict__ sumV, float* __restrict__ cvec,
        float* __restrict__ invn) {
    __shared__ __attribute__((aligned(16))) unsigned short la[2][8192];
    __shared__ __attribute__((aligned(16))) unsigned short lb[2][8192];
    int bid = blockIdx.x;
    int t = threadIdx.x;
    if (bid >= 640) {
        // ---- k2 body ----
        int i = (bid - 640) * 256 + t;   // 0..8191 = b*512 + n
        float s = 0.f, qq = 0.f;
        #pragma unroll 8
        for (int lt = 0; lt < 64; lt++) {
            s  += ps[(size_t)lt * 8192 + i];
            qq += pq[(size_t)lt * 8192 + i];
        }
        float inv = 1.0f / sqrtf(qq);
        sumV[i] = s;
        invn[i] = inv;
        cvec[i] = (s * inv + EPS) * inv;
        return;
    }
    // ---- k4 body (r13-proven; split-K=4, tr_b16 reads) ----
    int blk = (bid & 7) * 80 + (bid >> 3);  // XCD swizzle over 640-block partition
    int b = blk / 40;
    int rem = blk - b * 40;
    int pair = rem >> 2, split = rem & 3;
    int nt = (pair < 4) ? 0 : (pair < 7) ? 1 : (pair < 9) ? 2 : 3;
    int off = (nt * (9 - nt)) >> 1;
    int mt = nt + pair - off;
    bool diag = (nt == mt);
    int N0 = nt * 128, M0 = mt * 128;
    int w = t >> 6, lane = t & 63;
    int wr = w >> 1, wc = w & 1;
    int lr = lane & 15, q4 = lane >> 4;
    int srcRow = (lane >> 1) & 3;                    // l within lgrp
    int srcCol = (lane >> 3) * 16 + (lane & 1) * 8;  // n within 128
    const unsigned short* pa = Vb + ((size_t)b * LL + split * 1024) * HE + N0;
    const unsigned short* pb = Vb + ((size_t)b * LL + split * 1024) * HE + M0;
    unsigned laneTr = (unsigned)((lane >> 4) * 2048 + (lane & 15) * 8);
    unsigned rdA0 = lds_addr(&la[0][0]) + wr * 512 + laneTr;
    unsigned rdA1 = lds_addr(&la[1][0]) + wr * 512 + laneTr;
    unsigned rdB0 = (diag ? lds_addr(&la[0][0]) : lds_addr(&lb[0][0])) + wc * 512 + laneTr;
    unsigned rdB1 = (diag ? lds_addr(&la[1][0]) : lds_addr(&lb[1][0])) + wc * 512 + laneTr;
    f32x4 acc[4][4] = {};

#define STG(B, KB) do { \
    _Pragma("unroll") \
    for (int lg = 0; lg < 4; lg++) { \
        size_t ro = (size_t)((KB) * 64 + w * 16 + lg * 4 + srcRow) * HE + srcCol; \
        gl16(pa + ro, &la[B][(w * 4 + lg) * 512]); \
        if (!diag) gl16(pb + ro, &lb[B][(w * 4 + lg) * 512]); \
    } } while (0)

#define FRAGS_MFMA(KS, AADDR, BADDR) do { \
    u32x2 a0[4], a1[4], b0[4], b1[4]; \
    TRREAD(a0[0], AADDR, (KS)*8192 + 0*128);        TRREAD(a1[0], AADDR, (KS)*8192 + 0*128 + 1024); \
    TRREAD(a0[1], AADDR, (KS)*8192 + 1*128);        TRREAD(a1[1], AADDR, (KS)*8192 + 1*128 + 1024); \
    TRREAD(a0[2], AADDR, (KS)*8192 + 2*128);        TRREAD(a1[2], AADDR, (KS)*8192 + 2*128 + 1024); \
    TRREAD(a0[3], AADDR, (KS)*8192 + 3*128);        TRREAD(a1[3], AADDR, (KS)*8192 + 3*128 + 1024); \
    TRREAD(b0[0], BADDR, (KS)*8192 + 0*128);        TRREAD(b1[0], BADDR, (KS)*8192 + 0*128 + 1024); \
    TRREAD(b0[1], BADDR, (KS)*8192 + 1*128);        TRREAD(b1[1], BADDR, (KS)*8192 + 1*128 + 1024); \
    TRREAD(b0[2], BADDR, (KS)*8192 + 2*128);        TRREAD(b1[2], BADDR, (KS)*8192 + 2*128 + 1024); \
    TRREAD(b0[3], BADDR, (KS)*8192 + 3*128);        TRREAD(b1[3], BADDR, (KS)*8192 + 3*128 + 1024); \
    asm volatile("s_waitcnt lgkmcnt(0)" ::: "memory"); \
    __builtin_amdgcn_sched_barrier(0); \
    short8 af[4], bfr[4]; \
    _Pragma("unroll") \
    for (int i = 0; i < 4; i++) { \
        S8U ua; ua.u = (u32x4){a0[i].x, a0[i].y, a1[i].x, a1[i].y}; af[i] = ua.s; \
        S8U ub; ub.u = (u32x4){b0[i].x, b0[i].y, b1[i].x, b1[i].y}; bfr[i] = ub.s; \
    } \
    _Pragma("unroll") \
    for (int i = 0; i < 4; i++) \
        _Pragma("unroll") \
        for (int j = 0; j < 4; j++) \
            acc[i][j] = __builtin_amdgcn_mfma_f32_16x16x32_bf16(af[i], bfr[j], acc[i][j], 0, 0, 0); \
    } while (0)

    STG(0, 0);  // prologue
    #pragma unroll
    for (int kb = 0; kb < 16; kb++) {
        int cur = kb & 1;
        if (kb < 15) {
            STG(cur ^ 1, kb + 1);
            if (diag) { asm volatile("s_waitcnt vmcnt(4)" ::: "memory"); }
            else      { asm volatile("s_waitcnt vmcnt(8)" ::: "memory"); }
        } else {
            asm volatile("s_waitcnt vmcnt(0)" ::: "memory");
        }
        __builtin_amdgcn_s_barrier();
        __builtin_amdgcn_sched_barrier(0);
        unsigned aAd = cur ? rdA1 : rdA0;
        unsigned bAd = cur ? rdB1 : rdB0;
        FRAGS_MFMA(0, aAd, bAd);
        FRAGS_MFMA(1, aAd, bAd);
        __builtin_amdgcn_s_barrier();
    }
#undef STG
#undef FRAGS_MFMA
    // store bf16 partials, layout [ml*128 + nl] -> ushort4 along n
    size_t tbase = ((size_t)(b * 10 + pair) * 4 + split) * 16384;
    #pragma unroll
    for (int i = 0; i < 4; i++) {
        int nb = wr * 64 + i * 16 + q4 * 4;
        #pragma unroll
        for (int j = 0; j < 4; j++) {
            int ml = wc * 64 + j * 16 + lr;
            ushort4 wv;
            wv.x = f2bf(acc[i][j][0]); wv.y = f2bf(acc[i][j][1]);
            wv.z = f2bf(acc[i][j][2]); wv.w = f2bf(acc[i][j][3]);
            *(ushort4*)&Gp[tbase + (size_t)ml * 128 + nb] = wv;
        }
    }
}

// ---- kB: fused k5 (KQb reduce, blocks 0..159) + k3 (dvec GEMV, 160..2207) ----
__global__ __launch_bounds__(256) void kB_kq_dvec(
        const unsigned short* __restrict__ Gp, const float* __restrict__ invn,
        unsigned short* __restrict__ KQb, const unsigned short* __restrict__ Vb,
        const float* __restrict__ cvec, float* __restrict__ dvec) {
    __shared__ unsigned short lds_t[128][130];
    int bid = blockIdx.x;
    int t = threadIdx.x;
    if (bid >= 160) {
        // ---- k3 body ----
        int blk = bid - 160;
        int b = blk >> 7, lblk = blk & 127;
        int lloc = t >> 3, j = t & 7;
        int l = lblk * 32 + lloc;
        const unsigned short* rowp = Vb + ((size_t)b * LL + l) * HE + j * 64;
        const float* cp = cvec + b * HE + j * 64;
        float d = 0.f;
        #pragma unroll
        for (int g = 0; g < 8; g++) {
            short8 v = *(const short8*)(rowp + g * 8);
            float4 c0 = *(const float4*)(cp + g * 8);
            float4 c1 = *(const float4*)(cp + g * 8 + 4);
            d += bf2f((unsigned short)v[0]) * c0.x + bf2f((unsigned short)v[1]) * c0.y
               + bf2f((unsigned short)v[2]) * c0.z + bf2f((unsigned short)v[3]) * c0.w
               + bf2f((unsigned short)v[4]) * c1.x + bf2f((unsigned short)v[5]) * c1.y
               + bf2f((unsigned short)v[6]) * c1.z + bf2f((unsigned short)v[7]) * c1.w;
        }
        d += __shfl_xor(d, 1); d += __shfl_xor(d, 2); d += __shfl_xor(d, 4);
        if (j == 0) dvec[(size_t)b * LL + l] = d;
        return;
    }
    // ---- k5 body (split-4) ----
    int blk = bid;
    int b = blk / 10, pair = blk % 10;
    int nt = (pair < 4) ? 0 : (pair < 7) ? 1 : (pair < 9) ? 2 : 3;
    int off = (nt * (9 - nt)) >> 1;
    int mt = nt + pair - off;
    int N0 = nt * 128, M0 = mt * 128;
    const unsigned short* gp = Gp + ((size_t)(b * 10 + pair) * 4) * 16384;
    const float* inb = invn + (size_t)b * HE;
    #pragma unroll 2
    for (int e = 0; e < 32; e++) {
        int idx = e * 512 + t * 2;           // [ml][nl] pairs
        int ml = idx >> 7, nl = idx & 127;
        float s0 = 0.f, s1 = 0.f;
        #pragma unroll
        for (int sp = 0; sp < 4; sp++) {
            unsigned g2 = *(const unsigned*)&gp[(size_t)sp * 16384 + idx];
            s0 += bf2f((unsigned short)(g2 & 0xFFFF));
            s1 += bf2f((unsigned short)(g2 >> 16));
        }
        float im = inb[M0 + ml];
        ushort2 v;
        v.x = f2bf(s0 * inb[N0 + nl] * im);
        v.y = f2bf(s1 * inb[N0 + nl + 1] * im);
        *(ushort2*)&KQb[((size_t)b * HE + M0 + ml) * HE + N0 + nl] = v;
        *(ushort2*)&lds_t[ml][nl] = v;
    }
    __syncthreads();
    #pragma unroll 2
    for (int e = 0; e < 32; e++) {
        int idx = e * 512 + t * 2;
        int nl = idx >> 7, ml = idx & 127;   // transposed roles
        ushort2 v;
        v.x = lds_t[ml][nl];
        v.y = lds_t[ml + 1][nl];
        *(ushort2*)&KQb[((size_t)b * HE + N0 + nl) * HE + M0 + ml] = v;
    }
}

// ---- k6: part GEMM (KQb x Vb) + tailor/sumV/residual epilogue -----------
// r5/r10-proven: 2-phase double-buffered, counted vmcnt, 92 VGPR.
__global__ __launch_bounds__(256) void k6_part(const unsigned short* __restrict__ KQb,
        const unsigned short* __restrict__ Vb, const float* __restrict__ dvec,
        const float* __restrict__ sumV, const float* __restrict__ gamma,
        float* __restrict__ out) {
    __shared__ __attribute__((aligned(16))) unsigned short la[2][128][64];
    __shared__ __attribute__((aligned(16))) unsigned short lb[2][128][64];
    int cpx = gridDim.x >> 3;
    int blk = ((int)blockIdx.x & 7) * cpx + ((int)blockIdx.x >> 3);  // XCD swizzle
    int b = blk >> 7, mt = (blk >> 5) & 3, lt = blk & 31;
    int M0 = mt * 128, L0 = lt * 128;
    int t = threadIdx.x;
    int w = t >> 6, lane = t & 63;
    int wr = w >> 1, wc = w & 1;
    int rl = lane >> 3;
    int cl = ((lane & 7) ^ rl) << 3;
    int lr = lane & 15, q4 = lane >> 4;
    int ch0 = (q4 ^ (lane & 7)) << 3;
    const unsigned short* pa = KQb + ((size_t)b * HE + M0) * HE;
    const unsigned short* pb = Vb + ((size_t)b * LL + L0) * HE;
    float gma = gamma[0];   // hoisted above prologue so vmcnt counting stays exact
    f32x4 acc[4][4] = {};

#define STAGE6(B, KB) do { \
    int _k0 = (KB) * 64; \
    _Pragma("unroll") \
    for (int p = 0; p < 4; p++) { \
        int r0 = p * 32 + w * 8; \
        gl16(pa + (size_t)(r0 + rl) * HE + _k0 + cl, &la[B][r0][0]); \
        gl16(pb + (size_t)(r0 + rl) * HE + _k0 + cl, &lb[B][r0][0]); \
    } } while (0)

    STAGE6(0, 0);  // prologue
    #pragma unroll
    for (int kb = 0; kb < 8; kb++) {
        int cur = kb & 1;
        if (kb < 7) {
            STAGE6(cur ^ 1, kb + 1);
            asm volatile("s_waitcnt vmcnt(8)" ::: "memory");
        } else {
            asm volatile("s_waitcnt vmcnt(0)" ::: "memory");
        }
        __builtin_amdgcn_s_barrier();
        #pragma unroll
        for (int ks = 0; ks < 2; ks++) {
            int colA = ch0 ^ (ks << 5);
            short8 af[4], bfr[4];
            #pragma unroll
            for (int i = 0; i < 4; i++)
                af[i] = *(const short8*)&la[cur][wr*64 + i*16 + lr][colA];
            #pragma unroll
            for (int j = 0; j < 4; j++)
                bfr[j] = *(const short8*)&lb[cur][wc*64 + j*16 + lr][colA];
            #pragma unroll
            for (int i = 0; i < 4; i++)
                #pragma unroll
                for (int j = 0; j < 4; j++)
                    acc[i][j] = __builtin_amdgcn_mfma_f32_16x16x32_bf16(af[i], bfr[j], acc[i][j], 0, 0, 0);
        }
        __builtin_amdgcn_s_barrier();
    }
#undef STAGE6
    #pragma unroll
    for (int j = 0; j < 4; j++) {
        int lglob = L0 + wc*64 + j*16 + lr;
        float dt = dvec[(size_t)b * LL + lglob];
        float tailor = 1.0f / (512.0f + dt);
        #pragma unroll
        for (int i = 0; i < 4; i++) {
            int m4 = M0 + wr*64 + i*16 + q4*4;
            size_t ofs = ((size_t)b * LL + lglob) * HE + m4;
            ushort4 rv = *(const ushort4*)(Vb + ((size_t)b * LL + lglob) * HE + m4);
            float4 vs = *(const float4*)(sumV + (size_t)b * HE + m4);
            float4 o;
            o.x = bf2f(rv.x) + gma * (vs.x + acc[i][j][0]) * tailor;
            o.y = bf2f(rv.y) + gma * (vs.y + acc[i][j][1]) * tailor;
            o.z = bf2f(rv.z) + gma * (vs.z + acc[i][j][2]) * tailor;
            o.w = bf2f(rv.w) + gma * (vs.w + acc[i][j][3]) * tailor;
            *(float4*)(out + ofs) = o;
        }
    }
}

extern "C" void kernel_launch(void* const* d_in, const int* in_sizes, int n_in,
                              void* d_out, int out_size, void* d_ws, size_t ws_size,
                              hipStream_t stream) {
    const float* q     = (const float*)d_in[0];
    const float* gamma = (const float*)d_in[4];
    float* out = (float*)d_out;
    char* ws = (char*)d_ws;
    // ws layout (~122 MiB; proven r6)
    float* sumV  = (float*)(ws);                          // 32 KiB
    float* cvec  = (float*)(ws + 65536);                  // 32 KiB
    float* invn  = (float*)(ws + 98304);                  // 32 KiB
    float* dvec  = (float*)(ws + 131072);                 // 256 KiB
    unsigned short* KQb = (unsigned short*)(ws + 524288);      // 8 MiB
    unsigned short* Vb  = (unsigned short*)(ws + 8912896);     // 64 MiB
    unsigned short* Gp  = (unsigned short*)(ws + 76021760);    // 21 MiB (split-4)
    float* ps = (float*)(ws + 117964800);                 // 2 MiB
    float* pq = (float*)(ws + 120061952);                 // 2 MiB

    k1_stream   <<<1024, 256, 0, stream>>>(q, Vb, ps, pq);
    kA_gram_stats<<<672, 256, 0, stream>>>(Vb, Gp, ps, pq, sumV, cvec, invn);
    kB_kq_dvec  <<<2208, 256, 0, stream>>>(Gp, invn, KQb, Vb, cvec, dvec);
    k6_part     <<<2048, 256, 0, stream>>>(KQb, Vb, dvec, sumV, gamma, out);
}